// Round 3
// baseline (877.198 us; speedup 1.0000x reference)
//
#include <hip/hip_runtime.h>
#include <hip/hip_bf16.h>
#include <math.h>

#define S_LEN 2048
#define BATCH 2
#define NH 8
#define DH 64
#define DM 512
#define LOG2E 1.44269504088896f

typedef __attribute__((ext_vector_type(8))) short short8;
typedef __attribute__((ext_vector_type(4))) float floatx4;

__device__ __forceinline__ unsigned short f2bf(float f) {
  union { float f; unsigned u; } v; v.f = f;
  unsigned r = v.u + 0x7FFFu + ((v.u >> 16) & 1u);
  return (unsigned short)(r >> 16);
}

// packed f32x2 -> bf16x2 via v_cvt_pk_bf16_f32 (RNE, same as f2bf)
__device__ __forceinline__ unsigned pkbf(float a, float b) {
  __hip_bfloat162 h = __float22bfloat162_rn(make_float2(a, b));
  union { __hip_bfloat162 h; unsigned u; } v; v.h = h;
  return v.u;
}

// ---- all fp32->bf16 converts in ONE launch ----
// blocks [0,2048): input (2M elems); [2048,3072): 4 weight mats (256K each)
__global__ __launch_bounds__(256) void cvt_all(const float* __restrict__ in,
                                               const float* __restrict__ wq, const float* __restrict__ wk,
                                               const float* __restrict__ wv, const float* __restrict__ wo,
                                               unsigned short* __restrict__ in_bf,
                                               unsigned short* __restrict__ qw, unsigned short* __restrict__ kw,
                                               unsigned short* __restrict__ vw, unsigned short* __restrict__ ow) {
  int bid = blockIdx.x;
  const float* src; unsigned short* dst; int base;
  if (bid < 2048) { src = in; dst = in_bf; base = bid; }
  else {
    int wsel = (bid - 2048) >> 8;
    base = (bid - 2048) & 255;
    switch (wsel) {
      case 0: src = wq; dst = qw; break;
      case 1: src = wk; dst = kw; break;
      case 2: src = wv; dst = vw; break;
      default: src = wo; dst = ow; break;
    }
  }
  int i = base * 256 + threadIdx.x;
  float4 f = ((const float4*)src)[i];
  ((uint2*)dst)[i] = make_uint2(pkbf(f.x, f.y), pkbf(f.z, f.w));
}

// ---- FUSED: QKV bf16 GEMM (blocks [0,1536)) + topo-bias pass (blocks >=1536) ----
// GEMM: C[m,n] = (sum_k A[m,k]*W[n,k] + bias[n]) * scale ; z=0:Q (scaled), z=1:K, z=2:V transposed
// Bias: bias[b,s,t] = (dot(top[b,s,t,:],top_w)+top_b)*LOG2E, grid-strided.
// Rationale: bias pass is HBM-bound (537 MB read, MFMA idle); QKV GEMM is MFMA-bound.
// Co-residency overlaps the ~21us GEMM under the ~96us bias stream.
#define GEMM_BLKS 1536
#define BIAS_BLKS 8192
__global__ __launch_bounds__(256) void qkv_bias_fused(const unsigned short* __restrict__ A,
                                                      const unsigned short* __restrict__ W0,
                                                      const unsigned short* __restrict__ W1,
                                                      const unsigned short* __restrict__ W2,
                                                      const float* __restrict__ b0, const float* __restrict__ b1,
                                                      const float* __restrict__ b2,
                                                      void* __restrict__ o0, void* __restrict__ o1, void* __restrict__ o2,
                                                      float scale0,
                                                      const float* __restrict__ top,
                                                      const float* __restrict__ top_w,
                                                      const float* __restrict__ top_b,
                                                      float* __restrict__ bias_out) {
  __shared__ unsigned short As[64][72];
  __shared__ unsigned short Ws[64][72];
  const int bid = blockIdx.x;
  const int tid = threadIdx.x;

  if (bid >= GEMM_BLKS) {
    // ---- topo bias path ----
    const int bb = bid - GEMM_BLKS;
    const float4* wv4 = (const float4*)top_w;
    const float4 w0 = wv4[0], w1 = wv4[1], w2 = wv4[2], w3 = wv4[3];
    const float tb = top_b[0];
#pragma unroll
    for (int it = 0; it < 4; ++it) {
      const size_t e = ((size_t)(bb + it * BIAS_BLKS)) * 256 + tid;
      const float4* t = (const float4*)(top + e * 16);
      const float4 t0 = t[0], t1 = t[1], t2 = t[2], t3 = t[3];
      float acc = tb;
      acc += t0.x * w0.x + t0.y * w0.y + t0.z * w0.z + t0.w * w0.w;
      acc += t1.x * w1.x + t1.y * w1.y + t1.z * w1.z + t1.w * w1.w;
      acc += t2.x * w2.x + t2.y * w2.y + t2.z * w2.z + t2.w * w2.w;
      acc += t3.x * w3.x + t3.y * w3.y + t3.z * w3.z + t3.w * w3.w;
      bias_out[e] = acc * LOG2E;
    }
    return;
  }

  // ---- QKV GEMM path ----
  const int z = bid >> 9;           // 512 blocks per z
  const int r = bid & 511;
  const int m0 = (r & 63) * 64, n0 = (r >> 6) * 64;
  const unsigned short* W = (z == 0) ? W0 : (z == 1) ? W1 : W2;
  const float* bias = (z == 0) ? b0 : (z == 1) ? b1 : b2;
  void* out = (z == 0) ? o0 : (z == 1) ? o1 : o2;
  const int mode = (z == 2) ? 2 : 1;
  const float scale = (z == 0) ? scale0 : 1.0f;

  const int w = tid >> 6, l = tid & 63;
  const int lr = l & 15, lg = l >> 4;

  floatx4 acc[4];
#pragma unroll
  for (int nb = 0; nb < 4; nb++)
#pragma unroll
    for (int i = 0; i < 4; i++) acc[nb][i] = 0.f;

  const int srow = tid >> 2;
  const int sseg = (tid & 3) * 16;

  for (int k0 = 0; k0 < 512; k0 += 64) {
    const unsigned short* ap = A + (size_t)(m0 + srow) * 512 + k0 + sseg;
    const unsigned short* wp = W + (size_t)(n0 + srow) * 512 + k0 + sseg;
    *(short8*)&As[srow][sseg]     = *(const short8*)ap;
    *(short8*)&As[srow][sseg + 8] = *(const short8*)(ap + 8);
    *(short8*)&Ws[srow][sseg]     = *(const short8*)wp;
    *(short8*)&Ws[srow][sseg + 8] = *(const short8*)(wp + 8);
    __syncthreads();
#pragma unroll
    for (int kk = 0; kk < 2; kk++) {
      short8 af = *(const short8*)&As[w * 16 + lr][kk * 32 + lg * 8];
#pragma unroll
      for (int nb = 0; nb < 4; nb++) {
        short8 bf = *(const short8*)&Ws[nb * 16 + lr][kk * 32 + lg * 8];
        acc[nb] = __builtin_amdgcn_mfma_f32_16x16x32_bf16(af, bf, acc[nb], 0, 0, 0);
      }
    }
    __syncthreads();
  }

  if (mode == 2) {
    // stage as [d_local][s_local], coalesced 16B stores
#pragma unroll
    for (int nb = 0; nb < 4; nb++) {
      const float bv = bias[n0 + nb * 16 + lr];
      unsigned lo = pkbf(acc[nb][0] + bv, acc[nb][1] + bv);
      unsigned hi = pkbf(acc[nb][2] + bv, acc[nb][3] + bv);
      *(uint2*)&As[nb * 16 + lr][w * 16 + lg * 4] = make_uint2(lo, hi);
    }
    __syncthreads();
    const int b = m0 >> 11, s_base = m0 & 2047;
    const int h = n0 >> 6;
    unsigned short* outp = (unsigned short*)out + (size_t)(b * 8 + h) * DH * S_LEN;
    const int row = tid >> 2, seg = (tid & 3) * 16;
    short8 v0 = *(const short8*)&As[row][seg];
    short8 v1 = *(const short8*)&As[row][seg + 8];
    *(short8*)(outp + (size_t)row * S_LEN + s_base + seg)     = v0;
    *(short8*)(outp + (size_t)row * S_LEN + s_base + seg + 8) = v1;
    return;
  }

#pragma unroll
  for (int nb = 0; nb < 4; nb++) {
    const int n = n0 + nb * 16 + lr;
    const float bv = bias[n];
#pragma unroll
    for (int i = 0; i < 4; i++) {
      const int m = m0 + w * 16 + lg * 4 + i;
      float v = (acc[nb][i] + bv) * scale;
      const int b = m >> 11, s = m & 2047;
      const int h = n >> 6, d = n & 63;
      ((unsigned short*)out)[((size_t)(b * 8 + h) * 2048 + s) * 64 + d] = f2bf(v);
    }
  }
}

// ---- bf16 GEMM for O-projection: C[m,n] = sum_k A[m,k]*W[n,k] + bias[n], fp32 out ----
__global__ __launch_bounds__(256) void gemm_bt(const unsigned short* __restrict__ A,
                                               const unsigned short* __restrict__ W0,
                                               const float* __restrict__ b0,
                                               float* __restrict__ o0) {
  __shared__ unsigned short As[64][72];
  __shared__ unsigned short Ws[64][72];
  const int m0 = blockIdx.x * 64, n0 = blockIdx.y * 64;
  const int tid = threadIdx.x;
  const int w = tid >> 6, l = tid & 63;
  const int lr = l & 15, lg = l >> 4;

  floatx4 acc[4];
#pragma unroll
  for (int nb = 0; nb < 4; nb++)
#pragma unroll
    for (int i = 0; i < 4; i++) acc[nb][i] = 0.f;

  const int srow = tid >> 2;
  const int sseg = (tid & 3) * 16;

  for (int k0 = 0; k0 < 512; k0 += 64) {
    const unsigned short* ap = A + (size_t)(m0 + srow) * 512 + k0 + sseg;
    const unsigned short* wp = W0 + (size_t)(n0 + srow) * 512 + k0 + sseg;
    *(short8*)&As[srow][sseg]     = *(const short8*)ap;
    *(short8*)&As[srow][sseg + 8] = *(const short8*)(ap + 8);
    *(short8*)&Ws[srow][sseg]     = *(const short8*)wp;
    *(short8*)&Ws[srow][sseg + 8] = *(const short8*)(wp + 8);
    __syncthreads();
#pragma unroll
    for (int kk = 0; kk < 2; kk++) {
      short8 af = *(const short8*)&As[w * 16 + lr][kk * 32 + lg * 8];
#pragma unroll
      for (int nb = 0; nb < 4; nb++) {
        short8 bf = *(const short8*)&Ws[nb * 16 + lr][kk * 32 + lg * 8];
        acc[nb] = __builtin_amdgcn_mfma_f32_16x16x32_bf16(af, bf, acc[nb], 0, 0, 0);
      }
    }
    __syncthreads();
  }

#pragma unroll
  for (int nb = 0; nb < 4; nb++) {
    const int n = n0 + nb * 16 + lr;
    const float bv = b0[n];
#pragma unroll
    for (int i = 0; i < 4; i++) {
      const int m = m0 + w * 16 + lg * 4 + i;
      o0[(size_t)m * 512 + n] = acc[nb][i] + bv;
    }
  }
}

// ---- flash attention, transposed-S, log2-domain softmax ----
// Q pre-scaled by LOG2E/8, bias pre-scaled by LOG2E -> exp2 directly.
// T13 defer-max: skip O-rescale when tile max grew by <= 8 (P bounded by 2^8, safe in bf16).
__global__ __launch_bounds__(256) void attn_kernel(const unsigned short* __restrict__ Qb,
                                                   const unsigned short* __restrict__ Kb,
                                                   const unsigned short* __restrict__ Vt,
                                                   const float* __restrict__ biasb,
                                                   unsigned short* __restrict__ Ob) {
  __shared__ unsigned short Ps[4][16][72];  // wave-private, no barriers
  const int q0 = blockIdx.x * 64;
  const int bh = blockIdx.y;
  const int b = bh >> 3, h = bh & 7;
  const int tid = threadIdx.x;
  const int w = tid >> 6, l = tid & 63;
  const int lr = l & 15, lg = l >> 4;

  const unsigned short* Qh = Qb + (size_t)bh * S_LEN * DH;
  const unsigned short* Kh = Kb + (size_t)bh * S_LEN * DH;
  const unsigned short* Vh = Vt + (size_t)bh * DH * S_LEN;

  const int q = q0 + w * 16 + lr;
  short8 qf[2];
  qf[0] = *(const short8*)(Qh + (size_t)q * DH + lg * 8);
  qf[1] = *(const short8*)(Qh + (size_t)q * DH + 32 + lg * 8);

  float m_i = -1e30f, l_i = 0.f;
  floatx4 o[4];
#pragma unroll
  for (int nd = 0; nd < 4; nd++)
#pragma unroll
    for (int i = 0; i < 4; i++) o[nd][i] = 0.f;

  const float* brow = biasb + ((size_t)b * S_LEN + q) * S_LEN;

  for (int k0 = 0; k0 < S_LEN; k0 += 64) {
    floatx4 sa[4];
#pragma unroll
    for (int nb = 0; nb < 4; nb++)
#pragma unroll
      for (int i = 0; i < 4; i++) sa[nb][i] = 0.f;
    __builtin_amdgcn_s_setprio(1);
#pragma unroll
    for (int kk = 0; kk < 2; kk++) {
#pragma unroll
      for (int nb = 0; nb < 4; nb++) {
        short8 kf = *(const short8*)(Kh + (size_t)(k0 + nb * 16 + lr) * DH + kk * 32 + lg * 8);
        sa[nb] = __builtin_amdgcn_mfma_f32_16x16x32_bf16(kf, qf[kk], sa[nb], 0, 0, 0);
      }
    }
    __builtin_amdgcn_s_setprio(0);
    float p[4][4];
    float mx = -1e30f;
#pragma unroll
    for (int nb = 0; nb < 4; nb++) {
      float4 bv = *(const float4*)(brow + k0 + nb * 16 + lg * 4);
      p[nb][0] = sa[nb][0] + bv.x;
      p[nb][1] = sa[nb][1] + bv.y;
      p[nb][2] = sa[nb][2] + bv.z;
      p[nb][3] = sa[nb][3] + bv.w;
      mx = fmaxf(mx, fmaxf(fmaxf(p[nb][0], p[nb][1]), fmaxf(p[nb][2], p[nb][3])));
    }
    mx = fmaxf(mx, __shfl_xor(mx, 16));
    mx = fmaxf(mx, __shfl_xor(mx, 32));
    // T13 defer-max: per-row (lr) max is uniform over the 4 lg copies; __all makes
    // the branch wave-uniform. Deferred P <= 2^8 = 256, fine in bf16.
    const bool defer = (__all(mx <= m_i + 8.f) != 0);
    if (!defer) {
      const float mnew = fmaxf(m_i, mx);
      const float alpha = exp2f(m_i - mnew);
      l_i *= alpha;
#pragma unroll
      for (int nd = 0; nd < 4; nd++)
#pragma unroll
        for (int i = 0; i < 4; i++) o[nd][i] *= alpha;
      m_i = mnew;
    }
    float rs = 0.f;
#pragma unroll
    for (int nb = 0; nb < 4; nb++)
#pragma unroll
      for (int i = 0; i < 4; i++) {
        p[nb][i] = exp2f(p[nb][i] - m_i);
        rs += p[nb][i];
      }
    rs += __shfl_xor(rs, 16);
    rs += __shfl_xor(rs, 32);
    l_i += rs;
#pragma unroll
    for (int nb = 0; nb < 4; nb++) {
      unsigned lo = pkbf(p[nb][0], p[nb][1]);
      unsigned hi = pkbf(p[nb][2], p[nb][3]);
      *(uint2*)&Ps[w][lr][nb * 16 + lg * 4] = make_uint2(lo, hi);
    }
    __builtin_amdgcn_s_setprio(1);
#pragma unroll
    for (int kk = 0; kk < 2; kk++) {
      short8 pf = *(const short8*)&Ps[w][lr][kk * 32 + lg * 8];
#pragma unroll
      for (int nd = 0; nd < 4; nd++) {
        short8 vf = *(const short8*)(Vh + (size_t)(nd * 16 + lr) * S_LEN + k0 + kk * 32 + lg * 8);
        o[nd] = __builtin_amdgcn_mfma_f32_16x16x32_bf16(vf, pf, o[nd], 0, 0, 0);
      }
    }
    __builtin_amdgcn_s_setprio(0);
  }

  const float inv = 1.0f / l_i;
#pragma unroll
  for (int nd = 0; nd < 4; nd++) {
    unsigned lo = pkbf(o[nd][0] * inv, o[nd][1] * inv);
    unsigned hi = pkbf(o[nd][2] * inv, o[nd][3] * inv);
    *(uint2*)(Ob + ((size_t)b * S_LEN + q) * DM + h * DH + nd * 16 + lg * 4) = make_uint2(lo, hi);
  }
}

extern "C" void kernel_launch(void* const* d_in, const int* in_sizes, int n_in,
                              void* d_out, int out_size, void* d_ws, size_t ws_size,
                              hipStream_t stream) {
  const float* input = (const float*)d_in[0];
  const float* top   = (const float*)d_in[1];
  const float* top_w = (const float*)d_in[2];
  const float* top_b = (const float*)d_in[3];
  const float* wq = (const float*)d_in[4];
  const float* bq = (const float*)d_in[5];
  const float* wk = (const float*)d_in[6];
  const float* bk = (const float*)d_in[7];
  const float* wv = (const float*)d_in[8];
  const float* bv = (const float*)d_in[9];
  const float* wo = (const float*)d_in[10];
  const float* bo = (const float*)d_in[11];

  char* ws = (char*)d_ws;
  float* bias_ws = (float*)ws;              ws += (size_t)BATCH * S_LEN * S_LEN * 4;
  unsigned short* in_bf = (unsigned short*)ws;  ws += (size_t)BATCH * S_LEN * DM * 2;
  unsigned short* wq_bf = (unsigned short*)ws;  ws += (size_t)DM * DM * 2;
  unsigned short* wk_bf = (unsigned short*)ws;  ws += (size_t)DM * DM * 2;
  unsigned short* wv_bf = (unsigned short*)ws;  ws += (size_t)DM * DM * 2;
  unsigned short* wo_bf = (unsigned short*)ws;  ws += (size_t)DM * DM * 2;
  unsigned short* qb  = (unsigned short*)ws;    ws += (size_t)BATCH * NH * S_LEN * DH * 2;
  unsigned short* kb  = (unsigned short*)ws;    ws += (size_t)BATCH * NH * S_LEN * DH * 2;
  unsigned short* vtb = (unsigned short*)ws;    ws += (size_t)BATCH * NH * S_LEN * DH * 2;
  unsigned short* ob  = (unsigned short*)ws;    ws += (size_t)BATCH * S_LEN * DM * 2;

  cvt_all<<<3072, 256, 0, stream>>>(input, wq, wk, wv, wo, in_bf, wq_bf, wk_bf, wv_bf, wo_bf);

  qkv_bias_fused<<<GEMM_BLKS + BIAS_BLKS, 256, 0, stream>>>(
      in_bf, wq_bf, wk_bf, wv_bf, bq, bk, bv, qb, kb, vtb, 0.125f * LOG2E,
      top, top_w, top_b, bias_ws);

  attn_kernel<<<dim3(S_LEN / 64, BATCH * NH), 256, 0, stream>>>(qb, kb, vtb, bias_ws, ob);

  gemm_bt<<<dim3(4096 / 64, 512 / 64), 256, 0, stream>>>(ob, wo_bf, bo, (float*)d_out);
}

// Round 4
// 867.624 us; speedup vs baseline: 1.0110x; 1.0110x over previous
//
#include <hip/hip_runtime.h>
#include <hip/hip_bf16.h>
#include <math.h>

#define S_LEN 2048
#define BATCH 2
#define NH 8
#define DH 64
#define DM 512
#define LOG2E 1.44269504088896f

typedef __attribute__((ext_vector_type(8))) short short8;
typedef __attribute__((ext_vector_type(4))) float floatx4;

__device__ __forceinline__ unsigned short f2bf(float f) {
  union { float f; unsigned u; } v; v.f = f;
  unsigned r = v.u + 0x7FFFu + ((v.u >> 16) & 1u);
  return (unsigned short)(r >> 16);
}

// packed f32x2 -> bf16x2 via v_cvt_pk_bf16_f32 (RNE, same as f2bf)
__device__ __forceinline__ unsigned pkbf(float a, float b) {
  __hip_bfloat162 h = __float22bfloat162_rn(make_float2(a, b));
  union { __hip_bfloat162 h; unsigned u; } v; v.h = h;
  return v.u;
}

// ---- all fp32->bf16 converts in ONE launch ----
// blocks [0,2048): input (2M elems); [2048,3072): 4 weight mats (256K each)
__global__ __launch_bounds__(256) void cvt_all(const float* __restrict__ in,
                                               const float* __restrict__ wq, const float* __restrict__ wk,
                                               const float* __restrict__ wv, const float* __restrict__ wo,
                                               unsigned short* __restrict__ in_bf,
                                               unsigned short* __restrict__ qw, unsigned short* __restrict__ kw,
                                               unsigned short* __restrict__ vw, unsigned short* __restrict__ ow) {
  int bid = blockIdx.x;
  const float* src; unsigned short* dst; int base;
  if (bid < 2048) { src = in; dst = in_bf; base = bid; }
  else {
    int wsel = (bid - 2048) >> 8;
    base = (bid - 2048) & 255;
    switch (wsel) {
      case 0: src = wq; dst = qw; break;
      case 1: src = wk; dst = kw; break;
      case 2: src = wv; dst = vw; break;
      default: src = wo; dst = ow; break;
    }
  }
  int i = base * 256 + threadIdx.x;
  float4 f = ((const float4*)src)[i];
  ((uint2*)dst)[i] = make_uint2(pkbf(f.x, f.y), pkbf(f.z, f.w));
}

// ---- FUSED: QKV bf16 GEMM (blocks [0,1536)) + topo-bias pass (blocks >=1536) ----
#define GEMM_BLKS 1536
#define BIAS_BLKS 8192
__global__ __launch_bounds__(256) void qkv_bias_fused(const unsigned short* __restrict__ A,
                                                      const unsigned short* __restrict__ W0,
                                                      const unsigned short* __restrict__ W1,
                                                      const unsigned short* __restrict__ W2,
                                                      const float* __restrict__ b0, const float* __restrict__ b1,
                                                      const float* __restrict__ b2,
                                                      void* __restrict__ o0, void* __restrict__ o1, void* __restrict__ o2,
                                                      float scale0,
                                                      const float* __restrict__ top,
                                                      const float* __restrict__ top_w,
                                                      const float* __restrict__ top_b,
                                                      float* __restrict__ bias_out) {
  __shared__ unsigned short As[64][72];
  __shared__ unsigned short Ws[64][72];
  const int bid = blockIdx.x;
  const int tid = threadIdx.x;

  if (bid >= GEMM_BLKS) {
    // ---- topo bias path ----
    const int bb = bid - GEMM_BLKS;
    const float4* wv4 = (const float4*)top_w;
    const float4 w0 = wv4[0], w1 = wv4[1], w2 = wv4[2], w3 = wv4[3];
    const float tb = top_b[0];
#pragma unroll
    for (int it = 0; it < 4; ++it) {
      const size_t e = ((size_t)(bb + it * BIAS_BLKS)) * 256 + tid;
      const float4* t = (const float4*)(top + e * 16);
      const float4 t0 = t[0], t1 = t[1], t2 = t[2], t3 = t[3];
      float acc = tb;
      acc += t0.x * w0.x + t0.y * w0.y + t0.z * w0.z + t0.w * w0.w;
      acc += t1.x * w1.x + t1.y * w1.y + t1.z * w1.z + t1.w * w1.w;
      acc += t2.x * w2.x + t2.y * w2.y + t2.z * w2.z + t2.w * w2.w;
      acc += t3.x * w3.x + t3.y * w3.y + t3.z * w3.z + t3.w * w3.w;
      bias_out[e] = acc * LOG2E;
    }
    return;
  }

  // ---- QKV GEMM path ----
  const int z = bid >> 9;           // 512 blocks per z
  const int r = bid & 511;
  const int m0 = (r & 63) * 64, n0 = (r >> 6) * 64;
  const unsigned short* W = (z == 0) ? W0 : (z == 1) ? W1 : W2;
  const float* bias = (z == 0) ? b0 : (z == 1) ? b1 : b2;
  void* out = (z == 0) ? o0 : (z == 1) ? o1 : o2;
  const int mode = (z == 2) ? 2 : 1;
  const float scale = (z == 0) ? scale0 : 1.0f;

  const int w = tid >> 6, l = tid & 63;
  const int lr = l & 15, lg = l >> 4;

  floatx4 acc[4];
#pragma unroll
  for (int nb = 0; nb < 4; nb++)
#pragma unroll
    for (int i = 0; i < 4; i++) acc[nb][i] = 0.f;

  const int srow = tid >> 2;
  const int sseg = (tid & 3) * 16;

  for (int k0 = 0; k0 < 512; k0 += 64) {
    const unsigned short* ap = A + (size_t)(m0 + srow) * 512 + k0 + sseg;
    const unsigned short* wp = W + (size_t)(n0 + srow) * 512 + k0 + sseg;
    *(short8*)&As[srow][sseg]     = *(const short8*)ap;
    *(short8*)&As[srow][sseg + 8] = *(const short8*)(ap + 8);
    *(short8*)&Ws[srow][sseg]     = *(const short8*)wp;
    *(short8*)&Ws[srow][sseg + 8] = *(const short8*)(wp + 8);
    __syncthreads();
#pragma unroll
    for (int kk = 0; kk < 2; kk++) {
      short8 af = *(const short8*)&As[w * 16 + lr][kk * 32 + lg * 8];
#pragma unroll
      for (int nb = 0; nb < 4; nb++) {
        short8 bf = *(const short8*)&Ws[nb * 16 + lr][kk * 32 + lg * 8];
        acc[nb] = __builtin_amdgcn_mfma_f32_16x16x32_bf16(af, bf, acc[nb], 0, 0, 0);
      }
    }
    __syncthreads();
  }

  if (mode == 2) {
    // stage as [d_local][s_local], coalesced 16B stores
#pragma unroll
    for (int nb = 0; nb < 4; nb++) {
      const float bv = bias[n0 + nb * 16 + lr];
      unsigned lo = pkbf(acc[nb][0] + bv, acc[nb][1] + bv);
      unsigned hi = pkbf(acc[nb][2] + bv, acc[nb][3] + bv);
      *(uint2*)&As[nb * 16 + lr][w * 16 + lg * 4] = make_uint2(lo, hi);
    }
    __syncthreads();
    const int b = m0 >> 11, s_base = m0 & 2047;
    const int h = n0 >> 6;
    unsigned short* outp = (unsigned short*)out + (size_t)(b * 8 + h) * DH * S_LEN;
    const int row = tid >> 2, seg = (tid & 3) * 16;
    short8 v0 = *(const short8*)&As[row][seg];
    short8 v1 = *(const short8*)&As[row][seg + 8];
    *(short8*)(outp + (size_t)row * S_LEN + s_base + seg)     = v0;
    *(short8*)(outp + (size_t)row * S_LEN + s_base + seg + 8) = v1;
    return;
  }

#pragma unroll
  for (int nb = 0; nb < 4; nb++) {
    const int n = n0 + nb * 16 + lr;
    const float bv = bias[n];
#pragma unroll
    for (int i = 0; i < 4; i++) {
      const int m = m0 + w * 16 + lg * 4 + i;
      float v = (acc[nb][i] + bv) * scale;
      const int b = m >> 11, s = m & 2047;
      const int h = n >> 6, d = n & 63;
      ((unsigned short*)out)[((size_t)(b * 8 + h) * 2048 + s) * 64 + d] = f2bf(v);
    }
  }
}

// ---- bf16 GEMM for O-projection: C[m,n] = sum_k A[m,k]*W[n,k] + bias[n], fp32 out ----
__global__ __launch_bounds__(256) void gemm_bt(const unsigned short* __restrict__ A,
                                               const unsigned short* __restrict__ W0,
                                               const float* __restrict__ b0,
                                               float* __restrict__ o0) {
  __shared__ unsigned short As[64][72];
  __shared__ unsigned short Ws[64][72];
  const int m0 = blockIdx.x * 64, n0 = blockIdx.y * 64;
  const int tid = threadIdx.x;
  const int w = tid >> 6, l = tid & 63;
  const int lr = l & 15, lg = l >> 4;

  floatx4 acc[4];
#pragma unroll
  for (int nb = 0; nb < 4; nb++)
#pragma unroll
    for (int i = 0; i < 4; i++) acc[nb][i] = 0.f;

  const int srow = tid >> 2;
  const int sseg = (tid & 3) * 16;

  for (int k0 = 0; k0 < 512; k0 += 64) {
    const unsigned short* ap = A + (size_t)(m0 + srow) * 512 + k0 + sseg;
    const unsigned short* wp = W0 + (size_t)(n0 + srow) * 512 + k0 + sseg;
    *(short8*)&As[srow][sseg]     = *(const short8*)ap;
    *(short8*)&As[srow][sseg + 8] = *(const short8*)(ap + 8);
    *(short8*)&Ws[srow][sseg]     = *(const short8*)wp;
    *(short8*)&Ws[srow][sseg + 8] = *(const short8*)(wp + 8);
    __syncthreads();
#pragma unroll
    for (int kk = 0; kk < 2; kk++) {
      short8 af = *(const short8*)&As[w * 16 + lr][kk * 32 + lg * 8];
#pragma unroll
      for (int nb = 0; nb < 4; nb++) {
        short8 bf = *(const short8*)&Ws[nb * 16 + lr][kk * 32 + lg * 8];
        acc[nb] = __builtin_amdgcn_mfma_f32_16x16x32_bf16(af, bf, acc[nb], 0, 0, 0);
      }
    }
    __syncthreads();
  }

#pragma unroll
  for (int nb = 0; nb < 4; nb++) {
    const int n = n0 + nb * 16 + lr;
    const float bv = b0[n];
#pragma unroll
    for (int i = 0; i < 4; i++) {
      const int m = m0 + w * 16 + lg * 4 + i;
      o0[(size_t)m * 512 + n] = acc[nb][i] + bv;
    }
  }
}

// ---- flash attention: 128 q-rows/block (8 waves), XCD-swizzled grid ----
// Per-wave logic identical to the 4-wave version; K/V read once per 128 rows
// (halves K/V L2/L3 traffic) and same-XCD blocks share one head-pair's K/V
// (1 MB, L2-resident per XCD).
__global__ __launch_bounds__(512) void attn_kernel(const unsigned short* __restrict__ Qb,
                                                   const unsigned short* __restrict__ Kb,
                                                   const unsigned short* __restrict__ Vt,
                                                   const float* __restrict__ biasb,
                                                   unsigned short* __restrict__ Ob) {
  __shared__ unsigned short Ps[8][16][72];  // wave-private, no barriers
  // XCD swizzle: lin in [0,256); consecutive lin round-robin XCDs, so pin
  // bh to xcd = lin&7 (2 heads per XCD -> K+V 1MB resident in 4MB L2).
  const int lin = blockIdx.x;
  const int xcd = lin & 7, slot = lin >> 3;     // slot in [0,32)
  const int bh = xcd * 2 + (slot & 1);
  const int qt = slot >> 1;                     // [0,16)
  const int q0 = qt * 128;
  const int b = bh >> 3, h = bh & 7;
  const int tid = threadIdx.x;
  const int w = tid >> 6, l = tid & 63;         // w in [0,8)
  const int lr = l & 15, lg = l >> 4;

  const unsigned short* Qh = Qb + (size_t)bh * S_LEN * DH;
  const unsigned short* Kh = Kb + (size_t)bh * S_LEN * DH;
  const unsigned short* Vh = Vt + (size_t)bh * DH * S_LEN;

  const int q = q0 + w * 16 + lr;
  short8 qf[2];
  qf[0] = *(const short8*)(Qh + (size_t)q * DH + lg * 8);
  qf[1] = *(const short8*)(Qh + (size_t)q * DH + 32 + lg * 8);

  float m_i = -1e30f, l_i = 0.f;
  floatx4 o[4];
#pragma unroll
  for (int nd = 0; nd < 4; nd++)
#pragma unroll
    for (int i = 0; i < 4; i++) o[nd][i] = 0.f;

  const float* brow = biasb + ((size_t)b * S_LEN + q) * S_LEN;

  for (int k0 = 0; k0 < S_LEN; k0 += 64) {
    floatx4 sa[4];
#pragma unroll
    for (int nb = 0; nb < 4; nb++)
#pragma unroll
      for (int i = 0; i < 4; i++) sa[nb][i] = 0.f;
    __builtin_amdgcn_s_setprio(1);
#pragma unroll
    for (int kk = 0; kk < 2; kk++) {
#pragma unroll
      for (int nb = 0; nb < 4; nb++) {
        short8 kf = *(const short8*)(Kh + (size_t)(k0 + nb * 16 + lr) * DH + kk * 32 + lg * 8);
        sa[nb] = __builtin_amdgcn_mfma_f32_16x16x32_bf16(kf, qf[kk], sa[nb], 0, 0, 0);
      }
    }
    __builtin_amdgcn_s_setprio(0);
    float p[4][4];
    float mx = -1e30f;
#pragma unroll
    for (int nb = 0; nb < 4; nb++) {
      float4 bv = *(const float4*)(brow + k0 + nb * 16 + lg * 4);
      p[nb][0] = sa[nb][0] + bv.x;
      p[nb][1] = sa[nb][1] + bv.y;
      p[nb][2] = sa[nb][2] + bv.z;
      p[nb][3] = sa[nb][3] + bv.w;
      mx = fmaxf(mx, fmaxf(fmaxf(p[nb][0], p[nb][1]), fmaxf(p[nb][2], p[nb][3])));
    }
    mx = fmaxf(mx, __shfl_xor(mx, 16));
    mx = fmaxf(mx, __shfl_xor(mx, 32));
    // T13 defer-max: deferred P <= 2^8, safe in bf16.
    const bool defer = (__all(mx <= m_i + 8.f) != 0);
    if (!defer) {
      const float mnew = fmaxf(m_i, mx);
      const float alpha = exp2f(m_i - mnew);
      l_i *= alpha;
#pragma unroll
      for (int nd = 0; nd < 4; nd++)
#pragma unroll
        for (int i = 0; i < 4; i++) o[nd][i] *= alpha;
      m_i = mnew;
    }
    float rs = 0.f;
#pragma unroll
    for (int nb = 0; nb < 4; nb++)
#pragma unroll
      for (int i = 0; i < 4; i++) {
        p[nb][i] = exp2f(p[nb][i] - m_i);
        rs += p[nb][i];
      }
    rs += __shfl_xor(rs, 16);
    rs += __shfl_xor(rs, 32);
    l_i += rs;
#pragma unroll
    for (int nb = 0; nb < 4; nb++) {
      unsigned lo = pkbf(p[nb][0], p[nb][1]);
      unsigned hi = pkbf(p[nb][2], p[nb][3]);
      *(uint2*)&Ps[w][lr][nb * 16 + lg * 4] = make_uint2(lo, hi);
    }
    __builtin_amdgcn_s_setprio(1);
#pragma unroll
    for (int kk = 0; kk < 2; kk++) {
      short8 pf = *(const short8*)&Ps[w][lr][kk * 32 + lg * 8];
#pragma unroll
      for (int nd = 0; nd < 4; nd++) {
        short8 vf = *(const short8*)(Vh + (size_t)(nd * 16 + lr) * S_LEN + k0 + kk * 32 + lg * 8);
        o[nd] = __builtin_amdgcn_mfma_f32_16x16x32_bf16(vf, pf, o[nd], 0, 0, 0);
      }
    }
    __builtin_amdgcn_s_setprio(0);
  }

  const float inv = 1.0f / l_i;
#pragma unroll
  for (int nd = 0; nd < 4; nd++) {
    unsigned lo = pkbf(o[nd][0] * inv, o[nd][1] * inv);
    unsigned hi = pkbf(o[nd][2] * inv, o[nd][3] * inv);
    *(uint2*)(Ob + ((size_t)b * S_LEN + q) * DM + h * DH + nd * 16 + lg * 4) = make_uint2(lo, hi);
  }
}

extern "C" void kernel_launch(void* const* d_in, const int* in_sizes, int n_in,
                              void* d_out, int out_size, void* d_ws, size_t ws_size,
                              hipStream_t stream) {
  const float* input = (const float*)d_in[0];
  const float* top   = (const float*)d_in[1];
  const float* top_w = (const float*)d_in[2];
  const float* top_b = (const float*)d_in[3];
  const float* wq = (const float*)d_in[4];
  const float* bq = (const float*)d_in[5];
  const float* wk = (const float*)d_in[6];
  const float* bk = (const float*)d_in[7];
  const float* wv = (const float*)d_in[8];
  const float* bv = (const float*)d_in[9];
  const float* wo = (const float*)d_in[10];
  const float* bo = (const float*)d_in[11];

  char* ws = (char*)d_ws;
  float* bias_ws = (float*)ws;              ws += (size_t)BATCH * S_LEN * S_LEN * 4;
  unsigned short* in_bf = (unsigned short*)ws;  ws += (size_t)BATCH * S_LEN * DM * 2;
  unsigned short* wq_bf = (unsigned short*)ws;  ws += (size_t)DM * DM * 2;
  unsigned short* wk_bf = (unsigned short*)ws;  ws += (size_t)DM * DM * 2;
  unsigned short* wv_bf = (unsigned short*)ws;  ws += (size_t)DM * DM * 2;
  unsigned short* wo_bf = (unsigned short*)ws;  ws += (size_t)DM * DM * 2;
  unsigned short* qb  = (unsigned short*)ws;    ws += (size_t)BATCH * NH * S_LEN * DH * 2;
  unsigned short* kb  = (unsigned short*)ws;    ws += (size_t)BATCH * NH * S_LEN * DH * 2;
  unsigned short* vtb = (unsigned short*)ws;    ws += (size_t)BATCH * NH * S_LEN * DH * 2;
  unsigned short* ob  = (unsigned short*)ws;    ws += (size_t)BATCH * S_LEN * DM * 2;

  cvt_all<<<3072, 256, 0, stream>>>(input, wq, wk, wv, wo, in_bf, wq_bf, wk_bf, wv_bf, wo_bf);

  qkv_bias_fused<<<GEMM_BLKS + BIAS_BLKS, 256, 0, stream>>>(
      in_bf, wq_bf, wk_bf, wv_bf, bq, bk, bv, qb, kb, vtb, 0.125f * LOG2E,
      top, top_w, top_b, bias_ws);

  attn_kernel<<<256, 512, 0, stream>>>(qb, kb, vtb, bias_ws, ob);

  gemm_bt<<<dim3(4096 / 64, 512 / 64), 256, 0, stream>>>(ob, wo_bf, bo, (float*)d_out);
}